// Round 4
// baseline (324.151 us; speedup 1.0000x reference)
//
#include <hip/hip_runtime.h>
#include <hip/hip_bf16.h>

#define HALF_ROWS 262144
#define TAU 0.04f
#define BT_OFF 1024
#define LIST_OFF (BT_OFF + 320 * 512 * 2)   // 1024 + 327680

typedef __attribute__((ext_vector_type(8))) short s16x8;
typedef __attribute__((ext_vector_type(4))) unsigned short u16x4;
typedef __attribute__((ext_vector_type(4))) float f32x4;

__device__ __forceinline__ unsigned short f2bf(float f) {
  union { float f; unsigned u; } v; v.f = f;
  unsigned r = v.u + 0x7fffu + ((v.u >> 16) & 1u);   // RTNE
  return (unsigned short)(r >> 16);
}

// ---- prep: W1 -> Bf in MFMA-fragment order, zero counter ---------------------
// Bf linear idx = ((cb16*16 + ks)*64 + lane)*8 + j
//   col = cb16*16 + (lane&15);  k = ks*32 + (lane>>4)*8 + j
__global__ void moe_prep(const float* __restrict__ gw1, const float* __restrict__ aw1,
                         const float* __restrict__ bw1, unsigned short* __restrict__ Bf,
                         unsigned* __restrict__ cnt) {
  if (blockIdx.x == 0 && threadIdx.x == 0) *cnt = 0u;
  int idx = blockIdx.x * 512 + threadIdx.x;          // 320*512 = 163840
  int j = idx & 7, l = (idx >> 3) & 63, ks = (idx >> 9) & 15, cb = idx >> 13;
  int col = cb * 16 + (l & 15);
  int k = ks * 32 + ((l >> 4) << 3) + j;
  float v;
  if (col < 64)       v = gw1[k * 64 + col];
  else if (col < 192) v = aw1[k * 128 + (col - 64)];
  else                v = bw1[k * 128 + (col - 192)];
  Bf[idx] = f2bf(v);
}

// ---- main: 32 rows x 320 cols per block, 4 waves (1 col-group each) ----------
// 32KB LDS -> 5 blocks/CU; many small staggered blocks keep HBM pipe busy.
__global__ __launch_bounds__(256, 5) void moe_main(
    const float* __restrict__ x, const unsigned short* __restrict__ Bf,
    const float* __restrict__ gb1, const float* __restrict__ gw2, const float* __restrict__ gb2,
    const float* __restrict__ ab1, const float* __restrict__ aw2, const float* __restrict__ ab2,
    const float* __restrict__ bb1, const float* __restrict__ bw2, const float* __restrict__ bb2,
    float* __restrict__ out, unsigned* __restrict__ cnt, unsigned* __restrict__ list, int cap) {
  __shared__ unsigned short A[32 * 512];             // 32KB, XOR-swizzled

  const int tid = threadIdx.x;
  const long br = (long)blockIdx.x * 32;

  // ---- staging: 2 bursts x 8 independent 16B loads/thread ----
#pragma unroll 1
  for (int rnd = 0; rnd < 2; ++rnd) {
    f32x4 v[8];
#pragma unroll
    for (int u = 0; u < 8; ++u) {
      int i = tid + (rnd * 8 + u) * 256;
      int row = i >> 7, kq = i & 127;
      long roff = br + row + ((kq >> 6) ? (long)HALF_ROWS : 0L);
      v[u] = *(const f32x4*)(x + roff * 256 + (kq & 63) * 4);
    }
#pragma unroll
    for (int u = 0; u < 8; ++u) {
      int i = tid + (rnd * 8 + u) * 256;
      int row = i >> 7, kq = i & 127;
      u16x4 p;
      p[0] = f2bf(v[u][0]); p[1] = f2bf(v[u][1]);
      p[2] = f2bf(v[u][2]); p[3] = f2bf(v[u][3]);
      int byte = (row * 1024 + kq * 8) ^ ((row & 7) << 4);
      *(u16x4*)((char*)A + byte) = p;
    }
  }
  __syncthreads();

  const int w = tid >> 6, l = tid & 63;              // w = col-group 0..3
  const int lo = l & 15, hi = l >> 4;

  f32x4 acc[2][5];
#pragma unroll
  for (int i = 0; i < 2; i++)
#pragma unroll
    for (int j = 0; j < 5; j++) acc[i][j] = (f32x4){0.f, 0.f, 0.f, 0.f};

#pragma unroll 2
  for (int ks = 0; ks < 16; ++ks) {
    s16x8 bfr[5], afr[2];
#pragma unroll
    for (int ct = 0; ct < 5; ++ct)
      bfr[ct] = *(const s16x8*)(Bf + (((size_t)((w * 5 + ct) * 16 + ks)) << 9) + l * 8);
#pragma unroll
    for (int rt = 0; rt < 2; ++rt) {
      int row = rt * 16 + lo;
      int byte = (row * 1024 + ks * 64 + hi * 16) ^ ((lo & 7) << 4);
      afr[rt] = *(const s16x8*)((const char*)A + byte);
    }
#pragma unroll
    for (int rt = 0; rt < 2; ++rt)
#pragma unroll
      for (int ct = 0; ct < 5; ++ct)
        acc[rt][ct] = __builtin_amdgcn_mfma_f32_16x16x32_bf16(
            afr[rt], bfr[ct], acc[rt][ct], 0, 0, 0);
  }
  __syncthreads();                                   // before LDS reuse

  // ---- epilogue: bias+relu+3 tiny heads; head uniform per (w,ct) tile ---------
  float* part = (float*)A;                           // [32 rows][4 w][6] = 3KB
  float b1v[5], w0v[5], w1v[5];
  int head[5];
#pragma unroll
  for (int ct = 0; ct < 5; ++ct) {
    int c0 = w * 80 + ct * 16;
    int col = c0 + lo;
    int hd = c0 < 64 ? 0 : (c0 < 192 ? 1 : 2);
    head[ct] = hd;
    if (hd == 0)      { b1v[ct] = gb1[col];           w0v[ct] = gw2[col * 2];       w1v[ct] = gw2[col * 2 + 1]; }
    else if (hd == 1) { int c = col - 64;  b1v[ct] = ab1[c]; w0v[ct] = aw2[c * 2]; w1v[ct] = aw2[c * 2 + 1]; }
    else              { int c = col - 192; b1v[ct] = bb1[c]; w0v[ct] = bw2[c * 2]; w1v[ct] = bw2[c * 2 + 1]; }
  }
#pragma unroll
  for (int rt = 0; rt < 2; ++rt) {
    float pg0[4] = {0,0,0,0}, pg1[4] = {0,0,0,0};
    float pa0[4] = {0,0,0,0}, pa1[4] = {0,0,0,0};
    float pq0[4] = {0,0,0,0}, pq1[4] = {0,0,0,0};
#pragma unroll
    for (int ct = 0; ct < 5; ++ct)
#pragma unroll
      for (int j = 0; j < 4; ++j) {
        float h = fmaxf(acc[rt][ct][j] + b1v[ct], 0.f);
        float t0 = h * w0v[ct], t1 = h * w1v[ct];
        if (head[ct] == 0)      { pg0[j] += t0; pg1[j] += t1; }
        else if (head[ct] == 1) { pa0[j] += t0; pa1[j] += t1; }
        else                    { pq0[j] += t0; pq1[j] += t1; }
      }
#pragma unroll
    for (int m = 1; m < 16; m <<= 1)
#pragma unroll
      for (int j = 0; j < 4; ++j) {
        pg0[j] += __shfl_xor(pg0[j], m); pg1[j] += __shfl_xor(pg1[j], m);
        pa0[j] += __shfl_xor(pa0[j], m); pa1[j] += __shfl_xor(pa1[j], m);
        pq0[j] += __shfl_xor(pq0[j], m); pq1[j] += __shfl_xor(pq1[j], m);
      }
    if (lo == 0) {
#pragma unroll
      for (int j = 0; j < 4; ++j) {
        int r = rt * 16 + hi * 4 + j;
        float* pp = part + (r * 4 + w) * 6;
        pp[0] = pg0[j]; pp[1] = pg1[j]; pp[2] = pa0[j];
        pp[3] = pa1[j]; pp[4] = pq0[j]; pp[5] = pq1[j];
      }
    }
  }
  __syncthreads();

  if (tid < 32) {
    float g0 = 0, g1 = 0, a0 = 0, a1 = 0, e0 = 0, e1 = 0;
#pragma unroll
    for (int k2 = 0; k2 < 4; k2++) {
      float* pp = part + (tid * 4 + k2) * 6;
      g0 += pp[0]; g1 += pp[1]; a0 += pp[2]; a1 += pp[3]; e0 += pp[4]; e1 += pp[5];
    }
    float gl0 = g0 + gb2[0], gl1 = g1 + gb2[1];
    float fa0 = a0 + ab2[0], fa1 = a1 + ab2[1];
    float fb0 = e0 + bb2[0], fb1 = e1 + bb2[1];
    bool m0 = gl0 >= gl1;
    long grow = br + tid;
    f32x4 o;
    o[0] = m0 ? fa0 : 0.f; o[1] = m0 ? fa1 : 0.f;
    o[2] = m0 ? 0.f : fb0; o[3] = m0 ? 0.f : fb1;
    *(f32x4*)(out + grow * 4) = o;
    float diff = gl0 - gl1;
    if (fabsf(diff) < TAU && cap > 0) {
      unsigned u = atomicAdd(cnt, 1u);
      if (u < (unsigned)cap) {
        unsigned* e = list + (size_t)u * 8;
        e[0] = (unsigned)grow;
        float* ef = (float*)(e + 4);
        ef[0] = fa0; ef[1] = fa1; ef[2] = fb0; ef[3] = fb1;
      }
    }
  }
}

// ---- fixup: fp64 gate recompute for borderline rows --------------------------
__global__ void moe_fixup(const float* __restrict__ x,
                          const float* __restrict__ gw1, const float* __restrict__ gb1,
                          const float* __restrict__ gw2, const float* __restrict__ gb2,
                          float* __restrict__ out, const unsigned* __restrict__ cnt,
                          const unsigned* __restrict__ list, int cap) {
  unsigned n = *cnt;
  if (n > (unsigned)cap) n = (unsigned)cap;
  const int l = threadIdx.x & 63;
  const int wid = blockIdx.x * (blockDim.x >> 6) + (threadIdx.x >> 6);
  const int nw = gridDim.x * (blockDim.x >> 6);
  for (unsigned e = wid; e < n; e += nw) {
    const unsigned* ent = list + (size_t)e * 8;
    unsigned row = ent[0];
    const float* ef = (const float*)(ent + 4);
    const float* xr0 = x + (long)row * 256;
    const float* xr1 = x + ((long)row + HALF_ROWS) * 256;
    double a0 = 0.0, a1 = 0.0, a2 = 0.0, a3 = 0.0;
#pragma unroll 4
    for (int d = 0; d < 256; d += 4) {
      a0 += (double)xr0[d]     * (double)gw1[d * 64 + l];
      a1 += (double)xr0[d + 1] * (double)gw1[(d + 1) * 64 + l];
      a2 += (double)xr0[d + 2] * (double)gw1[(d + 2) * 64 + l];
      a3 += (double)xr0[d + 3] * (double)gw1[(d + 3) * 64 + l];
    }
#pragma unroll 4
    for (int d = 0; d < 256; d += 4) {
      a0 += (double)xr1[d]     * (double)gw1[(d + 256) * 64 + l];
      a1 += (double)xr1[d + 1] * (double)gw1[(d + 257) * 64 + l];
      a2 += (double)xr1[d + 2] * (double)gw1[(d + 258) * 64 + l];
      a3 += (double)xr1[d + 3] * (double)gw1[(d + 259) * 64 + l];
    }
    double h = a0 + a1 + a2 + a3 + (double)gb1[l];
    h = h > 0.0 ? h : 0.0;
    double t0 = h * (double)gw2[l * 2];
    double t1 = h * (double)gw2[l * 2 + 1];
#pragma unroll
    for (int m = 1; m < 64; m <<= 1) {
      t0 += __shfl_xor(t0, m);
      t1 += __shfl_xor(t1, m);
    }
    if (l == 0) {
      bool m0 = (t0 + (double)gb2[0]) >= (t1 + (double)gb2[1]);
      f32x4 o;
      o[0] = m0 ? ef[0] : 0.f; o[1] = m0 ? ef[1] : 0.f;
      o[2] = m0 ? 0.f : ef[2]; o[3] = m0 ? 0.f : ef[3];
      *(f32x4*)(out + (size_t)row * 4) = o;
    }
  }
}

extern "C" void kernel_launch(void* const* d_in, const int* in_sizes, int n_in,
                              void* d_out, int out_size, void* d_ws, size_t ws_size,
                              hipStream_t stream) {
  const float* x   = (const float*)d_in[0];
  const float* gw1 = (const float*)d_in[1];
  const float* gb1 = (const float*)d_in[2];
  const float* gw2 = (const float*)d_in[3];
  const float* gb2 = (const float*)d_in[4];
  const float* aw1 = (const float*)d_in[5];
  const float* ab1 = (const float*)d_in[6];
  const float* aw2 = (const float*)d_in[7];
  const float* ab2 = (const float*)d_in[8];
  const float* bw1 = (const float*)d_in[9];
  const float* bb1 = (const float*)d_in[10];
  const float* bw2 = (const float*)d_in[11];
  const float* bb2 = (const float*)d_in[12];
  float* out = (float*)d_out;

  unsigned char* ws = (unsigned char*)d_ws;
  unsigned* cnt = (unsigned*)ws;
  unsigned short* Bf = (unsigned short*)(ws + BT_OFF);
  unsigned* list = (unsigned*)(ws + LIST_OFF);
  long cap_l = ((long)ws_size - (long)LIST_OFF) / 32;
  int cap = cap_l < 0 ? 0 : (cap_l > 262144 ? 262144 : (int)cap_l);

  moe_prep<<<320, 512, 0, stream>>>(gw1, aw1, bw1, Bf, cnt);
  moe_main<<<8192, 256, 0, stream>>>(x, Bf, gb1, gw2, gb2, ab1, aw2, ab2,
                                     bb1, bw2, bb2, out, cnt, list, cap);
  moe_fixup<<<1024, 256, 0, stream>>>(x, gw1, gb1, gw2, gb2, out, cnt, list, cap);
}